// Round 1
// baseline (6425.121 us; speedup 1.0000x reference)
//
#include <hip/hip_runtime.h>
#include <stdint.h>

#define Bsz 256
#define Tlen 256
#define Idim 512
#define Hdim 1024

typedef __attribute__((ext_vector_type(8))) short bf16x8;
typedef __attribute__((ext_vector_type(16))) float f32x16;
typedef __attribute__((ext_vector_type(4))) float f32x4;
typedef __attribute__((ext_vector_type(4))) unsigned short u16x4;

__device__ __forceinline__ unsigned short f2b(float f) {
  union { float f; uint32_t u; } v; v.f = f;
  return (unsigned short)((v.u + 0x7FFFu + ((v.u >> 16) & 1u)) >> 16);
}
__device__ __forceinline__ float b2f(unsigned short u) {
  union { uint32_t u; float f; } v; v.u = ((uint32_t)u) << 16; return v.f;
}
__device__ __forceinline__ bf16x8 cvt8(f32x4 a, f32x4 b) {
  bf16x8 r;
  r[0] = (short)f2b(a[0]); r[1] = (short)f2b(a[1]);
  r[2] = (short)f2b(a[2]); r[3] = (short)f2b(a[3]);
  r[4] = (short)f2b(b[0]); r[5] = (short)f2b(b[1]);
  r[6] = (short)f2b(b[2]); r[7] = (short)f2b(b[3]);
  return r;
}

// ---------------------------------------------------------------------------
// Sort batches by seq_length (ascending) so batch-groups have quantile max
// lengths (masked work skipped). Also zeroes the per-group barrier counters.
// Robust to seq_lengths being stored as int32 or int64 (values < 256, so the
// int64 case shows all-zero odd 32-bit words; int32 case has random nonzeros).
// ---------------------------------------------------------------------------
__global__ void sort_kernel(const int* __restrict__ raw, int* __restrict__ perm,
                            int* __restrict__ lens_s, int* __restrict__ grp_max,
                            int* __restrict__ counters) {
  __shared__ int L[Bsz];
  __shared__ int S[Bsz];
  __shared__ int flag;
  const int b = threadIdx.x;
  if (b == 0) flag = 0;
  __syncthreads();
  int hi = raw[2 * b + 1];
  if (hi != 0) atomicOr(&flag, 1);
  __syncthreads();
  const int v = flag ? raw[b] : raw[2 * b];  // flag!=0 -> int32 layout
  L[b] = v;
  __syncthreads();
  int rank = 0;
  for (int i = 0; i < Bsz; ++i) {
    int li = L[i];
    rank += (li < v) || (li == v && i < b);
  }
  perm[rank] = b;
  lens_s[rank] = v;
  S[rank] = v;
  __syncthreads();
  if (b < 8) {
    grp_max[b] = S[b * 32 + 31];  // ascending -> last of group = max
    counters[b * 64] = 0;         // barrier counters (one cache line apart)
  }
}

__global__ void zero_kernel(f32x4* __restrict__ p) {
  f32x4 z = {0.f, 0.f, 0.f, 0.f};
  p[blockIdx.x * 256 + threadIdx.x] = z;
}

// ---------------------------------------------------------------------------
// Phase 1: xw[t][s][h] = x[perm[s]][t][:] @ Wx[t]^T + b[t]   (bf16 out)
// Block: 256 thr = 4 waves, tile 64 sorted-batches x 64 cols, K=512.
// Waves 2x2, each one 32x32 MFMA C-tile (v_mfma_f32_32x32x16_bf16, 32 steps).
// Early-exit when the whole sorted batch-tile is past its length.
// ---------------------------------------------------------------------------
__global__ __launch_bounds__(256) void xw_kernel(
    const float* __restrict__ x, const float* __restrict__ Wx,
    const float* __restrict__ bias, const int* __restrict__ perm,
    const int* __restrict__ lens_s, unsigned short* __restrict__ xw) {
  const int t = blockIdx.x;
  const int stile = blockIdx.y;   // 0..3  (64 sorted batches)
  const int ctile = blockIdx.z;   // 0..15 (64 cols)
  if (lens_s[stile * 64 + 63] <= t) return;  // whole tile masked at this t
  const int tid = threadIdx.x;
  const int lane = tid & 63;
  const int W = tid >> 6;         // wave 0..3; (W&1)=batch half, (W>>1)=col half
  const int m = lane & 31;
  const int q = lane >> 5;        // k-half selector
  const int srow = stile * 64 + (W & 1) * 32 + m;
  const int crow = ctile * 64 + (W >> 1) * 32 + m;
  const float* Ap = x + (size_t)perm[srow] * (Tlen * Idim) + (size_t)t * Idim + q * 8;
  const float* Bp = Wx + (size_t)t * (Hdim * Idim) + (size_t)crow * Idim + q * 8;
  f32x16 acc = {0.f,0.f,0.f,0.f,0.f,0.f,0.f,0.f,0.f,0.f,0.f,0.f,0.f,0.f,0.f,0.f};
#pragma unroll 4
  for (int kb = 0; kb < Idim; kb += 16) {
    f32x4 a0 = *(const f32x4*)(Ap + kb);
    f32x4 a1 = *(const f32x4*)(Ap + kb + 4);
    f32x4 b0 = *(const f32x4*)(Bp + kb);
    f32x4 b1 = *(const f32x4*)(Bp + kb + 4);
    acc = __builtin_amdgcn_mfma_f32_32x32x16_bf16(cvt8(a0, a1), cvt8(b0, b1), acc, 0, 0, 0);
  }
  // C layout (32x32): col = lane&31, row = (r&3) + 8*(r>>2) + 4*(lane>>5)
  const int cglob = ctile * 64 + (W >> 1) * 32 + m;
  const float bv = bias[t * Hdim + cglob];
  const int sbase = stile * 64 + (W & 1) * 32 + 4 * q;
#pragma unroll
  for (int r = 0; r < 16; ++r) {
    const int sg = sbase + (r & 3) + 8 * (r >> 2);
    xw[(size_t)t * (Bsz * Hdim) + (size_t)sg * Hdim + cglob] = f2b(acc[r] + bv);
  }
}

// ---------------------------------------------------------------------------
// Phase 2: recurrent. 8 groups (32 sorted batches each) x 32 col-blocks.
// group = blockIdx&7 -> same XCD under round-robin dispatch (locality only).
// Per step: C tile 32x32, K=1024 split over 4 waves (256 each), LDS-reduce,
// tanh + mask-select, double-buffered bf16 h, group-local atomic barrier.
// ---------------------------------------------------------------------------
__global__ __launch_bounds__(256) void rnn_kernel(
    const float* __restrict__ Wh, const unsigned short* __restrict__ xw,
    const int* __restrict__ lens_s, const int* __restrict__ grp_max,
    unsigned short* __restrict__ hbuf, float* __restrict__ hfin,
    int* __restrict__ counters) {
  const int bid = blockIdx.x;
  const int g = bid & 7;          // group / XCD
  const int j = bid >> 3;         // col slice 0..31
  const int tid = threadIdx.x;
  const int lane = tid & 63;
  const int W = tid >> 6;         // K-split wave id
  const int m = lane & 31;
  const int q = lane >> 5;
  const int cb = j * 32;
  const int Tg = grp_max[g];
  unsigned short* h0 = hbuf + (size_t)g * (32 * Hdim);
  unsigned short* h1 = hbuf + (size_t)(8 + g) * (32 * Hdim);
  __shared__ float cbuf[4][32][32];
  __shared__ int lensL[32];
  if (tid < 32) lensL[tid] = lens_s[g * 32 + tid];
  __syncthreads();
  const int erow = tid >> 3;      // epilogue row 0..31
  const int ec = (tid & 7) * 4;   // epilogue col base
  int* ctr = counters + g * 64;

  for (int t = 0; t < Tg; ++t) {
    const unsigned short* hc = (t & 1) ? h1 : h0;
    unsigned short* hn = (t & 1) ? h0 : h1;
    const unsigned short* Ap = hc + m * Hdim + W * 256 + q * 8;
    const float* Bp = Wh + (size_t)t * (Hdim * Hdim) + (size_t)(cb + m) * Hdim + W * 256 + q * 8;
    f32x16 acc = {0.f,0.f,0.f,0.f,0.f,0.f,0.f,0.f,0.f,0.f,0.f,0.f,0.f,0.f,0.f,0.f};
#pragma unroll 8
    for (int i = 0; i < 16; ++i) {
      bf16x8 af = *(const bf16x8*)(Ap + i * 16);
      f32x4 b0 = *(const f32x4*)(Bp + i * 16);
      f32x4 b1 = *(const f32x4*)(Bp + i * 16 + 4);
      acc = __builtin_amdgcn_mfma_f32_32x32x16_bf16(af, cvt8(b0, b1), acc, 0, 0, 0);
    }
#pragma unroll
    for (int r = 0; r < 16; ++r)
      cbuf[W][(r & 3) + 8 * (r >> 2) + 4 * q][m] = acc[r];
    __syncthreads();
    // reduce 4 K-partials, add xw, tanh, mask-select, write next h
    const unsigned short* xwp = xw + (size_t)t * (Bsz * Hdim) + (size_t)(g * 32 + erow) * Hdim + cb + ec;
    const unsigned short* hop = hc + erow * Hdim + cb + ec;
    unsigned short* hnp = hn + erow * Hdim + cb + ec;
    u16x4 xv = *(const u16x4*)xwp;
    u16x4 ov = *(const u16x4*)hop;
    const bool live = (t < lensL[erow]);
    u16x4 nv;
#pragma unroll
    for (int c = 0; c < 4; ++c) {
      float s = cbuf[0][erow][ec + c] + cbuf[1][erow][ec + c] +
                cbuf[2][erow][ec + c] + cbuf[3][erow][ec + c];
      s += b2f(xv[c]);
      nv[c] = live ? f2b(tanhf(s)) : ov[c];
    }
    *(u16x4*)hnp = nv;
    // group barrier: monotonic counter, agent-scope release/acquire
    __syncthreads();
    if (tid == 0) {
      __hip_atomic_fetch_add(ctr, 1, __ATOMIC_RELEASE, __HIP_MEMORY_SCOPE_AGENT);
      const int target = 32 * (t + 1);
      while (__hip_atomic_load(ctr, __ATOMIC_ACQUIRE, __HIP_MEMORY_SCOPE_AGENT) < target) {
        __builtin_amdgcn_s_sleep(1);
      }
    }
    __syncthreads();
  }
  // final h (own col-slice, written by this block or zero-init) -> fp32
  const unsigned short* hcf = (Tg & 1) ? h1 : h0;
  float* dst = hfin + (size_t)(g * 32 + erow) * Hdim + cb + ec;
  const unsigned short* srcp = hcf + erow * Hdim + cb + ec;
#pragma unroll
  for (int c = 0; c < 4; ++c) dst[c] = b2f(srcp[c]);
}

// ---------------------------------------------------------------------------
// out[perm[s]] = h_final[s] . W_out + b_out
// ---------------------------------------------------------------------------
__global__ __launch_bounds__(256) void out_kernel(
    const float* __restrict__ hfin, const float* __restrict__ Wo,
    const float* __restrict__ bo, const int* __restrict__ perm,
    float* __restrict__ out) {
  const int s = blockIdx.x;
  const int tid = threadIdx.x;
  const float* hr = hfin + (size_t)s * Hdim;
  float p = 0.f;
  for (int j = tid; j < Hdim; j += 256) p += hr[j] * Wo[j];
  for (int off = 32; off > 0; off >>= 1) p += __shfl_down(p, off, 64);
  __shared__ float r[4];
  if ((tid & 63) == 0) r[tid >> 6] = p;
  __syncthreads();
  if (tid == 0) out[perm[s]] = r[0] + r[1] + r[2] + r[3] + bo[0];
}

extern "C" void kernel_launch(void* const* d_in, const int* in_sizes, int n_in,
                              void* d_out, int out_size, void* d_ws, size_t ws_size,
                              hipStream_t stream) {
  (void)in_sizes; (void)n_in; (void)out_size; (void)ws_size;
  const float* x    = (const float*)d_in[0];
  const int*   sl   = (const int*)d_in[1];
  const float* Wx   = (const float*)d_in[2];
  const float* Wh   = (const float*)d_in[3];
  const float* bias = (const float*)d_in[4];
  const float* Wo   = (const float*)d_in[5];
  const float* bo   = (const float*)d_in[6];
  float* out = (float*)d_out;

  char* ws = (char*)d_ws;
  // workspace layout (136.3 MB total)
  unsigned short* xw   = (unsigned short*)ws;                          // 134,217,728 B
  unsigned short* hbuf = (unsigned short*)(ws + 134217728);            //   1,048,576 B
  float*          hfin = (float*)(ws + 134217728 + 1048576);           //   1,048,576 B
  int* perm     = (int*)(ws + 134217728 + 2097152);                    // 256 ints
  int* lens_s   = perm + 256;                                          // 256 ints
  int* grp_max  = lens_s + 256;                                        // 8 (padded 64)
  int* counters = grp_max + 64;                                        // 8 * 64 ints

  sort_kernel<<<1, 256, 0, stream>>>(sl, perm, lens_s, grp_max, counters);
  zero_kernel<<<256, 256, 0, stream>>>((f32x4*)hbuf);
  dim3 g1(Tlen, 4, 16);
  xw_kernel<<<g1, 256, 0, stream>>>(x, Wx, bias, perm, lens_s, xw);
  rnn_kernel<<<256, 256, 0, stream>>>(Wh, xw, lens_s, grp_max, hbuf, hfin, counters);
  out_kernel<<<Bsz, 256, 0, stream>>>(hfin, Wo, bo, perm, out);
}